// Round 6
// baseline (684.346 us; speedup 1.0000x reference)
//
#include <hip/hip_runtime.h>

// Mamba2 quantized decode step, MI355X/gfx950. Round 11.
// R10 (284.9us) post-mortem: chain = quantx -> fgemm1 -> kyf -> kepif -> fgemm2
// over a ~170us fixed harness floor. R11 shortens the chain:
//  - kysef = kyf + kepif merged: per batch-row, 32 blocks atomicMax their local
//    |y| max (uint bit-order, exact for >=0 floats) + bump a counter; the last
//    block re-reads the L2-hot yraw row and runs the full epilogue. Saves one
//    dispatch + gap and kepif's redundant per-block xBC scan.
//  - head-0 state prefetch issued BEFORE the zxb scan (loads are independent),
//    hiding scan latency under the HBM state stream.
//  - quantx zero-inits the per-row counter/max slots (workspace is poisoned).
// All quant math bit-identical to R10 (absmax 0.046875).

#define B_       64
#define DMODEL   2048
#define DSSM     4096
#define NH       64
#define HD       64
#define DSTATE   128
#define DPROJ    8512
#define XBCLEN   4352   // DSSM + 2*DSTATE

typedef __attribute__((ext_vector_type(4))) int int4v;
typedef __attribute__((ext_vector_type(4))) float f4v;

__device__ __forceinline__ float blockMax256(float v, float* sm) {
  #pragma unroll
  for (int off = 32; off > 0; off >>= 1)
    v = fmaxf(v, __shfl_xor(v, off, 64));
  __syncthreads();
  if ((threadIdx.x & 63) == 0) sm[threadIdx.x >> 6] = v;
  __syncthreads();
  return fmaxf(fmaxf(sm[0], sm[1]), fmaxf(sm[2], sm[3]));
}

__device__ __forceinline__ float absmax4(float4 v) {
  return fmaxf(fmaxf(fabsf(v.x), fabsf(v.y)), fmaxf(fabsf(v.z), fabsf(v.w)));
}

__device__ __forceinline__ float absmax4v(f4v v) {
  return fmaxf(fmaxf(fabsf(v.x), fabsf(v.y)), fmaxf(fabsf(v.z), fabsf(v.w)));
}

__device__ __forceinline__ float waveMax(float v) {
  #pragma unroll
  for (int off = 32; off > 0; off >>= 1)
    v = fmaxf(v, __shfl_xor(v, off, 64));
  return v;
}

__device__ __forceinline__ unsigned int pack4(float a, float b, float c, float d,
                                              float rs) {
  int c0 = (int)rintf(a * rs), c1 = (int)rintf(b * rs);
  int c2 = (int)rintf(c * rs), c3 = (int)rintf(d * rs);
  return (unsigned)(c0 & 255) | ((unsigned)(c1 & 255) << 8) |
         ((unsigned)(c2 & 255) << 16) | ((unsigned)(c3 & 255) << 24);
}

// ---------- quantize hidden (64 rows x 2048) -> int8 + scale; init row slots --
__global__ __launch_bounds__(256) void quantx(const float* __restrict__ in,
                                              unsigned int* __restrict__ outq,
                                              float* __restrict__ scales,
                                              unsigned* __restrict__ ymax_u,
                                              unsigned* __restrict__ cnt) {
  __shared__ float sm[4];
  int r = blockIdx.x;
  const float4* row = (const float4*)(in + (size_t)r * DMODEL);
  float4 v[2];
  float m = 0.f;
  #pragma unroll
  for (int i = 0; i < 2; i++) {
    v[i] = row[threadIdx.x + i * 256];
    m = fmaxf(m, absmax4(v[i]));
  }
  float mx = blockMax256(m, sm);
  float s = mx * (1.0f / 127.0f);
  float rs = (s == 0.f) ? 0.f : 127.0f / mx;
  if (s == 0.f) s = 1.f;
  if (threadIdx.x == 0) {
    scales[r] = s;
    ymax_u[r] = 0u;      // reset last-block reduction slots (ws is poisoned)
    cnt[r] = 0u;
  }
  unsigned int* orow = outq + (size_t)r * (DMODEL / 4);
  #pragma unroll
  for (int i = 0; i < 2; i++)
    orow[threadIdx.x + i * 256] = pack4(v[i].x, v[i].y, v[i].z, v[i].w, rs);
}

// ---------- fused quant+GEMM (R5 config) ----------
template<int K, int ROWS>
__global__ __launch_bounds__(256) void fgemm(const float* __restrict__ W,
                                             const char* __restrict__ Aq,
                                             const float* __restrict__ sA,
                                             float* __restrict__ Cout, int N) {
  constexpr int NF4 = K / 256;        // float4 per lane per row
  constexpr int RPW = ROWS / 4;       // rows per wave (4 waves)
  constexpr int LSTRIDE = K / 4 + 4;  // uints, padded vs bank conflicts
  __shared__ unsigned int wq[ROWS * LSTRIDE];
  __shared__ float smax[ROWS];
  int t = threadIdx.x, wave = t >> 6, lane = t & 63;
  int n0 = blockIdx.x * ROWS;
  #pragma unroll
  for (int rr = 0; rr < RPW; rr++) {
    int row = wave * RPW + rr;
    const f4v* rp = (const f4v*)(W + (size_t)(n0 + row) * K);
    f4v v[NF4];
    float m = 0.f;
    #pragma unroll
    for (int c = 0; c < NF4; c++) {
      v[c] = __builtin_nontemporal_load(&rp[lane + c * 64]);
      m = fmaxf(m, absmax4v(v[c]));
    }
    m = waveMax(m);
    float s = (m == 0.f) ? 1.f : m * (1.0f / 127.0f);
    float rs = (m == 0.f) ? 0.f : 127.0f / m;
    if (lane == 0) smax[row] = s;
    unsigned int* wrow = wq + row * LSTRIDE;
    #pragma unroll
    for (int c = 0; c < NF4; c++)
      wrow[lane + c * 64] = pack4(v[c].x, v[c].y, v[c].z, v[c].w, rs);
  }
  __syncthreads();
  int l16 = lane & 15, quad = lane >> 4;
  int4v acc = {0, 0, 0, 0};
  const char* arow = Aq + (size_t)(wave * 16 + l16) * K + quad * 16;
  const unsigned int* brow = wq + l16 * LSTRIDE + quad * 4;
  for (int k = 0; k < K; k += 256) {          // 4 MFMAs per iter, batched loads
    int4v af[4], bf[4];
    #pragma unroll
    for (int u = 0; u < 4; u++)
      af[u] = *(const int4v*)(arow + k + u * 64);
    #pragma unroll
    for (int u = 0; u < 4; u++) {
      int4v z = {0, 0, 0, 0};
      bf[u] = z;
      if (l16 < ROWS) bf[u] = *(const int4v*)(brow + (k + u * 64) / 4);
    }
    #pragma unroll
    for (int u = 0; u < 4; u++)
      acc = __builtin_amdgcn_mfma_i32_16x16x64_i8(af[u], bf[u], acc, 0, 0, 0);
  }
  if (l16 < ROWS) {
    float sw = smax[l16];
    #pragma unroll
    for (int r = 0; r < 4; r++) {
      int m = wave * 16 + quad * 4 + r;   // C/D: col=lane&15, row=quad*4+reg (m89)
      Cout[(size_t)m * N + n0 + l16] = (float)acc[r] * sA[m] * sw;
    }
  }
}

// ---------- kysef: SSM contraction + folded quant/coefs + last-block epilogue -
// grid (NH/2, B_): block handles 2 heads; 32 blocks per b-row; the block that
// bumps cnt[b] to 32 re-reads the (L2/L3-hot) yraw row and runs the epilogue.
__global__ __launch_bounds__(256) void kysef(const float* __restrict__ state,
                                             const float* __restrict__ zxb,
                                             const float* __restrict__ dt_bias,
                                             const float* __restrict__ A_log,
                                             const float* __restrict__ Dv,
                                             float* __restrict__ yraw,
                                             unsigned int* __restrict__ q3,
                                             float* __restrict__ sy,
                                             unsigned* __restrict__ ymax_u,
                                             unsigned* __restrict__ cnt) {
  __shared__ float sm[4];
  __shared__ unsigned oldS;
  int hx = blockIdx.x, b = blockIdx.y, t = threadIdx.x;
  int lane = t & 63;
  const float* prow = zxb + (size_t)b * DPROJ;
  const float4* p4 = (const float4*)prow;
  int h0 = hx * 2;
  // prefetch head-0 state BEFORE the scan (address-independent of it)
  const f4v* st0 = (const f4v*)(state + ((size_t)b * NH + h0) * (HD * DSTATE));
  f4v s4[8];
  #pragma unroll
  for (int j = 0; j < 8; j++) s4[j] = __builtin_nontemporal_load(&st0[j * 256 + t]);
  // xBC absmax: f4 idx [1024, 2112) -- bit-identical to kmid's (order-indep max)
  float m = 0.f;
  #pragma unroll
  for (int i = 0; i < 5; i++) {
    int idx = 1024 + t + i * 256;
    if (idx < 2112) m = fmaxf(m, absmax4(p4[idx]));
  }
  float mx = blockMax256(m, sm);
  float s = mx * (1.0f / 127.0f);
  float rs = (s == 0.f) ? 0.f : 127.0f / mx;
  if (s == 0.f) s = 1.f;
  // quantized C fragment for this lane (C = f4 idx [2080, 2112))
  float4 craw = p4[2080 + (t & 31)];
  float4 c4;
  c4.x = rintf(craw.x * rs) * s;
  c4.y = rintf(craw.y * rs) * s;
  c4.z = rintf(craw.z * rs) * s;
  c4.w = rintf(craw.w * rs) * s;
  // sbc = Bq . Cq (lanes 0..31, butterfly identical to kmid's)
  float p = 0.f;
  if (lane < 32) {
    float4 braw = p4[2048 + lane];
    float4 bq;
    bq.x = rintf(braw.x * rs) * s;
    bq.y = rintf(braw.y * rs) * s;
    bq.z = rintf(braw.z * rs) * s;
    bq.w = rintf(braw.w * rs) * s;
    p = bq.x * c4.x + bq.y * c4.y + bq.z * c4.z + bq.w * c4.w;
  }
  #pragma unroll
  for (int off = 1; off < 32; off <<= 1) p += __shfl_xor(p, off, 64);
  float sbc = __shfl(p, 0, 64);
  float ymy = 0.f;                       // this block's local max|y|
  #pragma unroll
  for (int hh = 0; hh < 2; hh++) {
    int h = h0 + hh;
    if (hh == 1) {                        // reload state regs for head 1
      const f4v* st1 = (const f4v*)(state + ((size_t)b * NH + h) * (HD * DSTATE));
      #pragma unroll
      for (int j = 0; j < 8; j++)
        s4[j] = __builtin_nontemporal_load(&st1[j * 256 + t]);
    }
    // coef (identical formulas to kmid)
    float dtv = prow[2 * DSSM + 2 * DSTATE + h] + dt_bias[h];
    if (dtv < -2.f) dtv = 0.f;
    else if (dtv <= 2.f)
      dtv = 0.6931471805599453f + 0.5f * dtv + dtv * dtv * (1.f / 8.f)
            + dtv * dtv * dtv * (1.f / 48.f);
    float A = -expf(A_log[h]);
    float dA = fmaxf(dtv * A, -10000.f);
    float e = 1.f + dA + dA * dA * (1.f / 2.f) + dA * dA * dA * (1.f / 6.f)
              + dA * dA * dA * dA * (1.f / 24.f)
              + dA * dA * dA * dA * dA * (1.f / 120.f);
    e = fminf(fmaxf(e, 0.f), 1.f);
    float coef = dtv * sbc;
    float acc[8];
    #pragma unroll
    for (int j = 0; j < 8; j++)
      acc[j] = s4[j].x * c4.x + s4[j].y * c4.y + s4[j].z * c4.z + s4[j].w * c4.w;
    #pragma unroll
    for (int off = 1; off < 32; off <<= 1) {
      #pragma unroll
      for (int j = 0; j < 8; j++) acc[j] += __shfl_xor(acc[j], off, 64);
    }
    if ((t & 31) == 0) {
      #pragma unroll
      for (int j = 0; j < 8; j++) {
        int r = j * 8 + (t >> 5);
        int d = h * HD + r;
        float xr = prow[DSSM + d];         // raw x; quantize on the fly
        float xq = rintf(xr * rs) * s;
        float yv = e * acc[j] + coef * xq;
        yraw[(size_t)b * DSSM + d] = yv;
        ymy = fmaxf(ymy, fabsf(yv));
      }
    }
  }
  // fold local |y| max into the per-row slot; last block runs the epilogue
  float mblk = blockMax256(ymy, sm);
  if (t == 0)
    __hip_atomic_fetch_max(&ymax_u[b], __float_as_uint(mblk),
                           __ATOMIC_RELAXED, __HIP_MEMORY_SCOPE_AGENT);
  __threadfence();                        // release our yraw writes + max
  unsigned old = 0;
  if (t == 0)
    old = __hip_atomic_fetch_add(&cnt[b], 1u, __ATOMIC_ACQ_REL,
                                 __HIP_MEMORY_SCOPE_AGENT);
  if (t == 0) oldS = old;
  __syncthreads();
  if (oldS != (NH / 2 - 1)) return;       // not the last block for row b
  __threadfence();                        // acquire: see all 32 blocks' yraw
  // ---------------- epilogue (exact kepif math; sq==s, rsq==rs) --------------
  float mx1 = __uint_as_float(
      __hip_atomic_load(&ymax_u[b], __ATOMIC_RELAXED, __HIP_MEMORY_SCOPE_AGENT));
  float s1 = mx1 * (1.0f / 127.0f);
  float rs1 = (s1 == 0.f) ? 0.f : 127.0f / mx1;
  if (s1 == 0.f) s1 = 1.f;
  const float* yrow = yraw + (size_t)b * DSSM;
  float4 y3[4];
  float m2 = 0.f;
  #pragma unroll
  for (int i = 0; i < 4; i++) {
    int fi = t + i * 256;                 // f4 idx within DSSM
    float4 yv4 = *(const float4*)(yrow + fi * 4);
    float4 xr = p4[1024 + fi];            // raw x from zxb
    float4 x4;
    x4.x = rintf(xr.x * rs) * s;
    x4.y = rintf(xr.y * rs) * s;
    x4.z = rintf(xr.z * rs) * s;
    x4.w = rintf(xr.w * rs) * s;
    float4 z4 = p4[fi];                   // raw z from zxb
    float4 d4 = ((const float4*)Dv)[fi];
    float4 r;
    r.x = (rintf(yv4.x * rs1) * s1 + d4.x * x4.x) * fmaxf(z4.x, 0.f);
    r.y = (rintf(yv4.y * rs1) * s1 + d4.y * x4.y) * fmaxf(z4.y, 0.f);
    r.z = (rintf(yv4.z * rs1) * s1 + d4.z * x4.z) * fmaxf(z4.z, 0.f);
    r.w = (rintf(yv4.w * rs1) * s1 + d4.w * x4.w) * fmaxf(z4.w, 0.f);
    y3[i] = r;
    m2 = fmaxf(m2, absmax4(r));
  }
  float mx3 = blockMax256(m2, sm);
  float s3 = mx3 * (1.0f / 127.0f);
  float rs3 = (s3 == 0.f) ? 0.f : 127.0f / mx3;
  if (s3 == 0.f) s3 = 1.f;
  if (t == 0) sy[b] = s3;
  unsigned int* orow = q3 + (size_t)b * (DSSM / 4);
  #pragma unroll
  for (int i = 0; i < 4; i++)
    orow[t + i * 256] = pack4(y3[i].x, y3[i].y, y3[i].z, y3[i].w, rs3);
}

extern "C" void kernel_launch(void* const* d_in, const int* in_sizes, int n_in,
                              void* d_out, int out_size, void* d_ws, size_t ws_size,
                              hipStream_t stream) {
  const float* hidden  = (const float*)d_in[0];
  const float* ssm     = (const float*)d_in[1];
  const float* W_in    = (const float*)d_in[2];
  const float* dt_bias = (const float*)d_in[3];
  const float* A_log   = (const float*)d_in[4];
  const float* Dv      = (const float*)d_in[5];
  const float* W_out   = (const float*)d_in[6];
  float* out = (float*)d_out;

  char* p = (char*)d_ws;
  auto alloc = [&](size_t bytes) {
    char* r = p;
    p += (bytes + 255) & ~(size_t)255;
    return r;
  };
  unsigned int* xq = (unsigned int*)alloc((size_t)B_ * DMODEL);
  unsigned int* q3 = (unsigned int*)alloc((size_t)B_ * DSSM);
  float* sx    = (float*)alloc(B_ * 4);
  float* sy    = (float*)alloc(B_ * 4);
  float* zxb   = (float*)alloc((size_t)B_ * DPROJ * 4);    // 2.2 MB
  float* yraw  = (float*)alloc((size_t)B_ * DSSM * 4);
  unsigned* ymax_u = (unsigned*)alloc(B_ * 4);
  unsigned* cnt    = (unsigned*)alloc(B_ * 4);

  quantx<<<B_, 256, 0, stream>>>(hidden, xq, sx, ymax_u, cnt);
  fgemm<DMODEL, 16><<<DPROJ / 16, 256, 0, stream>>>(W_in, (const char*)xq, sx,
                                                    zxb, DPROJ);
  kysef<<<dim3(NH / 2, B_), 256, 0, stream>>>(ssm, zxb, dt_bias, A_log, Dv,
                                              yraw, q3, sy, ymax_u, cnt);
  fgemm<DSSM, 4><<<DMODEL / 4, 256, 0, stream>>>(W_out, (const char*)q3, sy,
                                                 out, DMODEL);
}

// Round 7
// 285.254 us; speedup vs baseline: 2.3991x; 2.3991x over previous
//
#include <hip/hip_runtime.h>

// Mamba2 quantized decode step, MI355X/gfx950. Round 12 = revert to R10 (284.9us).
// R11 post-mortem: merging the epilogue into kysef collapsed VGPR to 32 ->
// state-load ILP gone (160 GB/s effective), plus device-scope fence storms;
// kysef hit 450us. The last-block pattern is wrong for a register-hungry HBM
// stream. This is the verified-best R10: 4 value kernels + quantx, kmid folded
// into kyf/kepif, nontemporal on read-once streams.
// All quant math bit-identical (absmax 0.046875).

#define B_       64
#define DMODEL   2048
#define DSSM     4096
#define NH       64
#define HD       64
#define DSTATE   128
#define DPROJ    8512
#define XBCLEN   4352   // DSSM + 2*DSTATE

typedef __attribute__((ext_vector_type(4))) int int4v;
typedef __attribute__((ext_vector_type(4))) float f4v;

__device__ __forceinline__ float blockMax256(float v, float* sm) {
  #pragma unroll
  for (int off = 32; off > 0; off >>= 1)
    v = fmaxf(v, __shfl_xor(v, off, 64));
  __syncthreads();
  if ((threadIdx.x & 63) == 0) sm[threadIdx.x >> 6] = v;
  __syncthreads();
  return fmaxf(fmaxf(sm[0], sm[1]), fmaxf(sm[2], sm[3]));
}

__device__ __forceinline__ float absmax4(float4 v) {
  return fmaxf(fmaxf(fabsf(v.x), fabsf(v.y)), fmaxf(fabsf(v.z), fabsf(v.w)));
}

__device__ __forceinline__ float absmax4v(f4v v) {
  return fmaxf(fmaxf(fabsf(v.x), fabsf(v.y)), fmaxf(fabsf(v.z), fabsf(v.w)));
}

__device__ __forceinline__ float waveMax(float v) {
  #pragma unroll
  for (int off = 32; off > 0; off >>= 1)
    v = fmaxf(v, __shfl_xor(v, off, 64));
  return v;
}

__device__ __forceinline__ unsigned int pack4(float a, float b, float c, float d,
                                              float rs) {
  int c0 = (int)rintf(a * rs), c1 = (int)rintf(b * rs);
  int c2 = (int)rintf(c * rs), c3 = (int)rintf(d * rs);
  return (unsigned)(c0 & 255) | ((unsigned)(c1 & 255) << 8) |
         ((unsigned)(c2 & 255) << 16) | ((unsigned)(c3 & 255) << 24);
}

// ---------- quantize hidden (64 rows x 2048) -> int8 + scale ----------
__global__ __launch_bounds__(256) void quantx(const float* __restrict__ in,
                                              unsigned int* __restrict__ outq,
                                              float* __restrict__ scales) {
  __shared__ float sm[4];
  int r = blockIdx.x;
  const float4* row = (const float4*)(in + (size_t)r * DMODEL);
  float4 v[2];
  float m = 0.f;
  #pragma unroll
  for (int i = 0; i < 2; i++) {
    v[i] = row[threadIdx.x + i * 256];
    m = fmaxf(m, absmax4(v[i]));
  }
  float mx = blockMax256(m, sm);
  float s = mx * (1.0f / 127.0f);
  float rs = (s == 0.f) ? 0.f : 127.0f / mx;
  if (s == 0.f) s = 1.f;
  if (threadIdx.x == 0) scales[r] = s;
  unsigned int* orow = outq + (size_t)r * (DMODEL / 4);
  #pragma unroll
  for (int i = 0; i < 2; i++)
    orow[threadIdx.x + i * 256] = pack4(v[i].x, v[i].y, v[i].z, v[i].w, rs);
}

// ---------- fused quant+GEMM (R5 config) ----------
template<int K, int ROWS>
__global__ __launch_bounds__(256) void fgemm(const float* __restrict__ W,
                                             const char* __restrict__ Aq,
                                             const float* __restrict__ sA,
                                             float* __restrict__ Cout, int N) {
  constexpr int NF4 = K / 256;        // float4 per lane per row
  constexpr int RPW = ROWS / 4;       // rows per wave (4 waves)
  constexpr int LSTRIDE = K / 4 + 4;  // uints, padded vs bank conflicts
  __shared__ unsigned int wq[ROWS * LSTRIDE];
  __shared__ float smax[ROWS];
  int t = threadIdx.x, wave = t >> 6, lane = t & 63;
  int n0 = blockIdx.x * ROWS;
  #pragma unroll
  for (int rr = 0; rr < RPW; rr++) {
    int row = wave * RPW + rr;
    const f4v* rp = (const f4v*)(W + (size_t)(n0 + row) * K);
    f4v v[NF4];
    float m = 0.f;
    #pragma unroll
    for (int c = 0; c < NF4; c++) {
      v[c] = __builtin_nontemporal_load(&rp[lane + c * 64]);
      m = fmaxf(m, absmax4v(v[c]));
    }
    m = waveMax(m);
    float s = (m == 0.f) ? 1.f : m * (1.0f / 127.0f);
    float rs = (m == 0.f) ? 0.f : 127.0f / m;
    if (lane == 0) smax[row] = s;
    unsigned int* wrow = wq + row * LSTRIDE;
    #pragma unroll
    for (int c = 0; c < NF4; c++)
      wrow[lane + c * 64] = pack4(v[c].x, v[c].y, v[c].z, v[c].w, rs);
  }
  __syncthreads();
  int l16 = lane & 15, quad = lane >> 4;
  int4v acc = {0, 0, 0, 0};
  const char* arow = Aq + (size_t)(wave * 16 + l16) * K + quad * 16;
  const unsigned int* brow = wq + l16 * LSTRIDE + quad * 4;
  for (int k = 0; k < K; k += 256) {          // 4 MFMAs per iter, batched loads
    int4v af[4], bf[4];
    #pragma unroll
    for (int u = 0; u < 4; u++)
      af[u] = *(const int4v*)(arow + k + u * 64);
    #pragma unroll
    for (int u = 0; u < 4; u++) {
      int4v z = {0, 0, 0, 0};
      bf[u] = z;
      if (l16 < ROWS) bf[u] = *(const int4v*)(brow + (k + u * 64) / 4);
    }
    #pragma unroll
    for (int u = 0; u < 4; u++)
      acc = __builtin_amdgcn_mfma_i32_16x16x64_i8(af[u], bf[u], acc, 0, 0, 0);
  }
  if (l16 < ROWS) {
    float sw = smax[l16];
    #pragma unroll
    for (int r = 0; r < 4; r++) {
      int m = wave * 16 + quad * 4 + r;   // C/D: col=lane&15, row=quad*4+reg (m89)
      Cout[(size_t)m * N + n0 + l16] = (float)acc[r] * sA[m] * sw;
    }
  }
}

// ---------- ky: SSM contraction with folded kmid quant/coef work ----------
// grid (NH/2, B_): each block computes scale once, handles 2 heads (64KB state).
__global__ __launch_bounds__(256) void kyf(const float* __restrict__ state,
                                           const float* __restrict__ zxb,
                                           const float* __restrict__ dt_bias,
                                           const float* __restrict__ A_log,
                                           float* __restrict__ yraw) {
  __shared__ float sm[4];
  int hx = blockIdx.x, b = blockIdx.y, t = threadIdx.x;
  int lane = t & 63;
  const float* prow = zxb + (size_t)b * DPROJ;
  const float4* p4 = (const float4*)prow;
  // xBC absmax: f4 idx [1024, 2112) -- bit-identical to kmid's (max is
  // order-independent)
  float m = 0.f;
  #pragma unroll
  for (int i = 0; i < 5; i++) {
    int idx = 1024 + t + i * 256;
    if (idx < 2112) m = fmaxf(m, absmax4(p4[idx]));
  }
  float mx = blockMax256(m, sm);
  float s = mx * (1.0f / 127.0f);
  float rs = (s == 0.f) ? 0.f : 127.0f / mx;
  if (s == 0.f) s = 1.f;
  // quantized C fragment for this lane (C = f4 idx [2080, 2112))
  float4 craw = p4[2080 + (t & 31)];
  float4 c4;
  c4.x = rintf(craw.x * rs) * s;
  c4.y = rintf(craw.y * rs) * s;
  c4.z = rintf(craw.z * rs) * s;
  c4.w = rintf(craw.w * rs) * s;
  // sbc = Bq . Cq (lanes 0..31, butterfly identical to kmid's)
  float p = 0.f;
  if (lane < 32) {
    float4 braw = p4[2048 + lane];
    float4 bq;
    bq.x = rintf(braw.x * rs) * s;
    bq.y = rintf(braw.y * rs) * s;
    bq.z = rintf(braw.z * rs) * s;
    bq.w = rintf(braw.w * rs) * s;
    p = bq.x * c4.x + bq.y * c4.y + bq.z * c4.z + bq.w * c4.w;
  }
  #pragma unroll
  for (int off = 1; off < 32; off <<= 1) p += __shfl_xor(p, off, 64);
  float sbc = __shfl(p, 0, 64);
  #pragma unroll
  for (int hh = 0; hh < 2; hh++) {
    int h = hx * 2 + hh;
    // coef (identical formulas to kmid)
    float dtv = prow[2 * DSSM + 2 * DSTATE + h] + dt_bias[h];
    if (dtv < -2.f) dtv = 0.f;
    else if (dtv <= 2.f)
      dtv = 0.6931471805599453f + 0.5f * dtv + dtv * dtv * (1.f / 8.f)
            + dtv * dtv * dtv * (1.f / 48.f);
    float A = -expf(A_log[h]);
    float dA = fmaxf(dtv * A, -10000.f);
    float e = 1.f + dA + dA * dA * (1.f / 2.f) + dA * dA * dA * (1.f / 6.f)
              + dA * dA * dA * dA * (1.f / 24.f)
              + dA * dA * dA * dA * dA * (1.f / 120.f);
    e = fminf(fmaxf(e, 0.f), 1.f);
    float coef = dtv * sbc;
    const f4v* st = (const f4v*)(state + ((size_t)b * NH + h) * (HD * DSTATE));
    f4v s4[8];
    #pragma unroll
    for (int j = 0; j < 8; j++) s4[j] = __builtin_nontemporal_load(&st[j * 256 + t]);
    float acc[8];
    #pragma unroll
    for (int j = 0; j < 8; j++)
      acc[j] = s4[j].x * c4.x + s4[j].y * c4.y + s4[j].z * c4.z + s4[j].w * c4.w;
    #pragma unroll
    for (int off = 1; off < 32; off <<= 1) {
      #pragma unroll
      for (int j = 0; j < 8; j++) acc[j] += __shfl_xor(acc[j], off, 64);
    }
    if ((t & 31) == 0) {
      #pragma unroll
      for (int j = 0; j < 8; j++) {
        int r = j * 8 + (t >> 5);
        int d = h * HD + r;
        float xr = prow[DSSM + d];            // raw x; quantize on the fly
        float xq = rintf(xr * rs) * s;
        yraw[(size_t)b * DSSM + d] = e * acc[j] + coef * xq;
      }
    }
  }
}

// ---------- epilogue with folded x-quant: fq(y) -> +D*x -> *relu(z) -> fq ----
__global__ __launch_bounds__(256) void kepif(const float* __restrict__ yraw,
                                             const float* __restrict__ zxb,
                                             const float* __restrict__ Dv,
                                             unsigned int* __restrict__ q3,
                                             float* __restrict__ sy) {
  __shared__ float sm[4];
  int b = blockIdx.x, t = threadIdx.x;
  const float4* p4 = (const float4*)(zxb + (size_t)b * DPROJ);
  // xBC absmax (same deterministic scan as kyf/kmid)
  float mq = 0.f;
  #pragma unroll
  for (int i = 0; i < 5; i++) {
    int idx = 1024 + t + i * 256;
    if (idx < 2112) mq = fmaxf(mq, absmax4(p4[idx]));
  }
  float mxq = blockMax256(mq, sm);
  float sq = mxq * (1.0f / 127.0f);
  float rsq = (sq == 0.f) ? 0.f : 127.0f / mxq;
  if (sq == 0.f) sq = 1.f;
  const float* yrow = yraw + (size_t)b * DSSM;
  float4 yv[4];
  float m = 0.f;
  #pragma unroll
  for (int i = 0; i < 4; i++) {
    yv[i] = *(const float4*)(yrow + t * 4 + i * 1024);
    m = fmaxf(m, absmax4(yv[i]));
  }
  float mx1 = blockMax256(m, sm);
  float s1 = mx1 * (1.0f / 127.0f);
  float rs1 = (s1 == 0.f) ? 0.f : 127.0f / mx1;
  if (s1 == 0.f) s1 = 1.f;
  float4 y3[4];
  float m2 = 0.f;
  #pragma unroll
  for (int i = 0; i < 4; i++) {
    int fi = t + i * 256;                     // f4 idx within DSSM
    float4 xr = p4[1024 + fi];                // raw x from zxb
    float4 x4;
    x4.x = rintf(xr.x * rsq) * sq;
    x4.y = rintf(xr.y * rsq) * sq;
    x4.z = rintf(xr.z * rsq) * sq;
    x4.w = rintf(xr.w * rsq) * sq;
    float4 z4 = p4[fi];                       // raw z from zxb
    float4 d4 = ((const float4*)Dv)[fi];
    float4 r;
    r.x = (rintf(yv[i].x * rs1) * s1 + d4.x * x4.x) * fmaxf(z4.x, 0.f);
    r.y = (rintf(yv[i].y * rs1) * s1 + d4.y * x4.y) * fmaxf(z4.y, 0.f);
    r.z = (rintf(yv[i].z * rs1) * s1 + d4.z * x4.z) * fmaxf(z4.z, 0.f);
    r.w = (rintf(yv[i].w * rs1) * s1 + d4.w * x4.w) * fmaxf(z4.w, 0.f);
    y3[i] = r;
    m2 = fmaxf(m2, absmax4(r));
  }
  float mx3 = blockMax256(m2, sm);
  float s3 = mx3 * (1.0f / 127.0f);
  float rs3 = (s3 == 0.f) ? 0.f : 127.0f / mx3;
  if (s3 == 0.f) s3 = 1.f;
  if (t == 0) sy[b] = s3;
  unsigned int* orow = q3 + (size_t)b * (DSSM / 4);
  #pragma unroll
  for (int i = 0; i < 4; i++)
    orow[t + i * 256] = pack4(y3[i].x, y3[i].y, y3[i].z, y3[i].w, rs3);
}

extern "C" void kernel_launch(void* const* d_in, const int* in_sizes, int n_in,
                              void* d_out, int out_size, void* d_ws, size_t ws_size,
                              hipStream_t stream) {
  const float* hidden  = (const float*)d_in[0];
  const float* ssm     = (const float*)d_in[1];
  const float* W_in    = (const float*)d_in[2];
  const float* dt_bias = (const float*)d_in[3];
  const float* A_log   = (const float*)d_in[4];
  const float* Dv      = (const float*)d_in[5];
  const float* W_out   = (const float*)d_in[6];
  float* out = (float*)d_out;

  char* p = (char*)d_ws;
  auto alloc = [&](size_t bytes) {
    char* r = p;
    p += (bytes + 255) & ~(size_t)255;
    return r;
  };
  unsigned int* xq = (unsigned int*)alloc((size_t)B_ * DMODEL);
  unsigned int* q3 = (unsigned int*)alloc((size_t)B_ * DSSM);
  float* sx    = (float*)alloc(B_ * 4);
  float* sy    = (float*)alloc(B_ * 4);
  float* zxb   = (float*)alloc((size_t)B_ * DPROJ * 4);    // 2.2 MB
  float* yraw  = (float*)alloc((size_t)B_ * DSSM * 4);

  quantx<<<B_, 256, 0, stream>>>(hidden, xq, sx);
  fgemm<DMODEL, 16><<<DPROJ / 16, 256, 0, stream>>>(W_in, (const char*)xq, sx,
                                                    zxb, DPROJ);
  kyf<<<dim3(NH / 2, B_), 256, 0, stream>>>(ssm, zxb, dt_bias, A_log, yraw);
  kepif<<<B_, 256, 0, stream>>>(yraw, zxb, Dv, q3, sy);
  fgemm<DSSM, 4><<<DMODEL / 4, 256, 0, stream>>>(W_out, (const char*)q3, sy,
                                                 out, DMODEL);
}